// Round 1
// baseline (106.285 us; speedup 1.0000x reference)
//
#include <hip/hip_runtime.h>

// Problem constants
#define NROWS 8192   // 4 * 2048
#define DIM   512
#define NT    64                    // 8192 / 128 tiles per side
#define NTRI  (NT * (NT + 1) / 2)   // 2080 upper-triangular tile blocks
#define NACC  64                    // accumulator slots (contention spread)

typedef __attribute__((ext_vector_type(16))) float f32x16;
typedef __attribute__((ext_vector_type(8)))  int   i32x8;

// Software fp32 -> OCP e4m3fn, round-to-nearest-even (r7/r8-verified).
__device__ __forceinline__ unsigned char f2e4m3(float x) {
    unsigned ux = __float_as_uint(x);
    unsigned s  = (ux >> 24) & 0x80u;
    float a = __uint_as_float(ux & 0x7FFFFFFFu);     // |x|, finite for our data
    a = fminf(a, 448.0f);                            // clamp to max finite
    unsigned ua = __float_as_uint(a);
    int eb = (int)(ua >> 23);                        // biased exponent
    if (eb < 121) eb = 121;                          // denormal region: step 2^-9
    float step  = __uint_as_float((unsigned)(eb - 3) << 23);    // 2^(eb-130)
    float istep = __uint_as_float((unsigned)(257 - eb) << 23);  // 2^(130-eb), exact
    float q = rintf(a * istep) * step;               // RNE on e4m3 grid
    q = fminf(q, 448.0f);
    if (q < 0.001953125f)                            // below min denormal 2^-9 -> 0
        return (unsigned char)s;
    unsigned uq = __float_as_uint(q);
    int eq = (int)(uq >> 23) - 127;
    unsigned byte;
    if (eq < -6) byte = (unsigned)(q * 512.0f);      // denormal: d*2^-9, d in 1..7
    else         byte = (unsigned)((eq + 7) << 3) | ((uq >> 20) & 7u);
    return (unsigned char)(s | byte);
}

// Kernel 1: fp32 row norms + fp32->fp8 conversion into a pre-swizzled global
// layout for BK=64 slabs: within each 64B k-slab of row r, 8B chunk c is
// stored at position c ^ (r&7). GEMM staging is then a straight LINEAR copy
// (global_load_lds-compatible, rule #21: inverse-swz source + linear dest +
// swz read) and frag reads sit at the ds_read_b64 bank floor.
__global__ __launch_bounds__(256) void norm_convert_kernel(
    const float* __restrict__ X, unsigned char* __restrict__ Xq,
    float* __restrict__ norms, float* __restrict__ acc)
{
    const int tid  = threadIdx.x;
    const int lane = tid & 63;
    const int w    = tid >> 6;
    const int row  = blockIdx.x * 4 + w;

    if (blockIdx.x == 0 && tid < NACC) acc[tid] = 0.0f;

    const float* xr = X + (size_t)row * DIM + lane * 8;
    float4 v0 = *(const float4*)xr;
    float4 v1 = *(const float4*)(xr + 4);

    float s = 0.0f;
    s = fmaf(v0.x, v0.x, s); s = fmaf(v0.y, v0.y, s);
    s = fmaf(v0.z, v0.z, s); s = fmaf(v0.w, v0.w, s);
    s = fmaf(v1.x, v1.x, s); s = fmaf(v1.y, v1.y, s);
    s = fmaf(v1.z, v1.z, s); s = fmaf(v1.w, v1.w, s);

    union { unsigned char b[8]; uint2 v; } pk;
    pk.b[0] = f2e4m3(v0.x); pk.b[1] = f2e4m3(v0.y);
    pk.b[2] = f2e4m3(v0.z); pk.b[3] = f2e4m3(v0.w);
    pk.b[4] = f2e4m3(v1.x); pk.b[5] = f2e4m3(v1.y);
    pk.b[6] = f2e4m3(v1.z); pk.b[7] = f2e4m3(v1.w);

    const int slab = lane >> 3;                      // 64B slab index (0..7)
    const int cpos = (lane & 7) ^ (row & 7);         // swizzled 8B position
    *(uint2*)(Xq + (size_t)row * DIM + slab * 64 + cpos * 8) = pk.v;

    #pragma unroll
    for (int off = 32; off > 0; off >>= 1) s += __shfl_down(s, off, 64);
    if (lane == 0) norms[row] = s;
}

// Async global->LDS DMA, 16B/lane (dest = wave-uniform base + lane*16).
__device__ __forceinline__ void gload16(const void* g, void* l) {
    __builtin_amdgcn_global_load_lds(
        (const __attribute__((address_space(1))) unsigned int*)g,
        (__attribute__((address_space(3))) unsigned int*)l, 16, 0, 0);
}

// Kernel 2: upper-triangular tiled X·X^T + fused sqrt/exp/sum epilogue.
// 128x128 tile/block, 4 waves, 64x64 quadrant/wave.
//
// r9 changes (theory: 6.39M LDS bank conflicts were the 16-way-conflicted
// staging ds_write_b128s, NOT the frag reads; MFMA pipe demand was 36%):
//  (a) staging via global_load_lds width=16 (lane-linear LDS writes ->
//      conflict-free, no staging VALU, no prefetch VGPRs). Global data is
//      pre-swizzled so LDS stays a linear copy (m151/m97 pattern).
//  (b) compute via MX-scaled mfma_scale_f32_32x32x64_f8f6f4, scales = 1.0
//      (E8M0 0x7F): 2x the non-scaled fp8 rate, K=64 matches the slab.
//      A/B frag: row = lane&31, k-bytes (lane>>5)*32..+31 (chunks 4q+i at
//      swizzled pos ^(lane&7)); C/D: col=lane&31,
//      row=(reg&3)+8*(reg>>2)+4*(lane>>5) (shape-determined, m101/m127).
// LDS: 2 x (8KB A + 8KB B) = 32KB -> 4 blocks/CU at (256,4).
// NO device-scope fences (r3: agent fence = per-XCD L2 flush, +40us).
__global__ __launch_bounds__(256, 4) void pair_loss_gemm_kernel(
    const unsigned char* __restrict__ Xq, const float* __restrict__ norms,
    float* __restrict__ acc)
{
    __shared__ __align__(16) char As0[8192];
    __shared__ __align__(16) char As1[8192];
    __shared__ __align__(16) char Bs0[8192];
    __shared__ __align__(16) char Bs1[8192];
    __shared__ float wsum[4];

    // decode linear block id -> upper-triangular (bi, bj), bi <= bj
    int t = blockIdx.x, bi = 0;
    while (t >= (NT - bi)) { t -= (NT - bi); bi++; }
    const int bj = bi + t;

    const int tid  = threadIdx.x;
    const int lane = tid & 63;
    const int w    = tid >> 6;

    const int rowA = bi * 128;
    const int rowB = bj * 128;

    f32x16 accv[2][2];
    #pragma unroll
    for (int a = 0; a < 2; a++)
        #pragma unroll
        for (int b = 0; b < 2; b++)
            #pragma unroll
            for (int r = 0; r < 16; r++) accv[a][b][r] = 0.0f;

    // staging sources: per wave-call, lane covers row rs = w*32 + (lane>>2)
    // (and +16 for the second 1KB call), bytes (lane&3)*16 of the 64B slab.
    const int rs = w * 32 + (lane >> 2);
    const int cs = (lane & 3) * 16;
    const unsigned char* sA0 = Xq + (size_t)(rowA + rs) * DIM + cs;
    const unsigned char* sA1 = sA0 + (size_t)16 * DIM;
    const unsigned char* sB0 = Xq + (size_t)(rowB + rs) * DIM + cs;
    const unsigned char* sB1 = sB0 + (size_t)16 * DIM;
    const int ldw = w * 2048;                        // wave's 2KB LDS segment

    // MFMA frag addressing: row rl = lane&31, k-half qh = lane>>5 (32B),
    // chunk (4*qh+i) at swizzled byte pos ((4*qh+i)^(lane&7))*8.
    const int rl = lane & 31;
    const int qh = lane >> 5;
    const int sw = lane & 7;
    const int wr = (w & 1) * 64;
    const int wc = (w >> 1) * 64;
    const int raoff = (wr + rl) * 64;
    const int rboff = (wc + rl) * 64;

    // prologue: DMA slab 0 (compiler drains vmcnt before the barrier)
    gload16(sA0, As0 + ldw);
    gload16(sA1, As0 + ldw + 1024);
    gload16(sB0, Bs0 + ldw);
    gload16(sB1, Bs0 + ldw + 1024);
    __syncthreads();

    char* curA = As0; char* nxtA = As1;
    char* curB = Bs0; char* nxtB = Bs1;

    #pragma unroll 1
    for (int k = 0; k < 8; k++) {
        const bool more = (k < 7);
        if (more) {                                  // DMA next slab first
            const int ko = (k + 1) * 64;
            gload16(sA0 + ko, nxtA + ldw);
            gload16(sA1 + ko, nxtA + ldw + 1024);
            gload16(sB0 + ko, nxtB + ldw);
            gload16(sB1 + ko, nxtB + ldw + 1024);
        }

        union { long l[4]; i32x8 v; } fa0, fa1, fb0, fb1;
        #pragma unroll
        for (int i = 0; i < 4; i++) {
            const int fo = ((4 * qh + i) ^ sw) * 8;
            fa0.l[i] = *(const long*)(curA + raoff + fo);
            fa1.l[i] = *(const long*)(curA + raoff + 2048 + fo);
            fb0.l[i] = *(const long*)(curB + rboff + fo);
            fb1.l[i] = *(const long*)(curB + rboff + 2048 + fo);
        }

        accv[0][0] = __builtin_amdgcn_mfma_scale_f32_32x32x64_f8f6f4(
            fa0.v, fb0.v, accv[0][0], 0, 0, 0, 0x7F7F7F7F, 0, 0x7F7F7F7F);
        accv[0][1] = __builtin_amdgcn_mfma_scale_f32_32x32x64_f8f6f4(
            fa0.v, fb1.v, accv[0][1], 0, 0, 0, 0x7F7F7F7F, 0, 0x7F7F7F7F);
        accv[1][0] = __builtin_amdgcn_mfma_scale_f32_32x32x64_f8f6f4(
            fa1.v, fb0.v, accv[1][0], 0, 0, 0, 0x7F7F7F7F, 0, 0x7F7F7F7F);
        accv[1][1] = __builtin_amdgcn_mfma_scale_f32_32x32x64_f8f6f4(
            fa1.v, fb1.v, accv[1][1], 0, 0, 0, 0x7F7F7F7F, 0, 0x7F7F7F7F);

        if (more) {
            __syncthreads();                         // vmcnt+lgkm drained here
            char* tA = curA; curA = nxtA; nxtA = tA;
            char* tB = curB; curB = nxtB; nxtB = tB;
        }
    }

    // epilogue: term = exp(-0.1*sqrt(max(ni+nj-2*dot, 0))); diag -> 1
    // 32x32 C/D: col = lane&31, row = (reg&3) + 8*(reg>>2) + 4*(lane>>5)
    const float wgt = (bi == bj) ? 1.0f : 2.0f;
    const int cl = lane & 31;
    const int rh = (lane >> 5) * 4;
    float lsum = 0.0f;
    #pragma unroll
    for (int a = 0; a < 2; a++) {
        const int gia = rowA + wr + a * 32;
        float ni[16];
        #pragma unroll
        for (int r = 0; r < 16; r++)
            ni[r] = norms[gia + (r & 3) + 8 * (r >> 2) + rh];
        #pragma unroll
        for (int b = 0; b < 2; b++) {
            const int gj = rowB + wc + b * 32 + cl;
            const float nj = norms[gj];
            #pragma unroll
            for (int r = 0; r < 16; r++) {
                const int gi = gia + (r & 3) + 8 * (r >> 2) + rh;
                float sq = fmaf(-2.0f, accv[a][b][r], ni[r] + nj);
                sq = fmaxf(sq, 0.0f);
                float term = __expf(-0.1f * sqrtf(sq));
                if (gi == gj) term = 1.0f;
                lsum += term;
            }
        }
    }
    lsum *= wgt;
    #pragma unroll
    for (int off = 32; off > 0; off >>= 1) lsum += __shfl_down(lsum, off, 64);
    if (lane == 0) wsum[w] = lsum;
    __syncthreads();
    if (tid == 0)
        atomicAdd(&acc[blockIdx.x & (NACC - 1)],
                  wsum[0] + wsum[1] + wsum[2] + wsum[3]);
}

// Kernel 3: finalize scalar outputs (sum NACC slots)
__global__ void finalize_kernel(const float* __restrict__ acc,
                                float* __restrict__ out)
{
    const int lane = threadIdx.x;
    float s = (lane < NACC) ? acc[lane] : 0.0f;
    #pragma unroll
    for (int off = 32; off > 0; off >>= 1) s += __shfl_down(s, off, 64);
    if (lane == 0) {
        const float inv = 1.0f / ((float)NROWS * (float)NROWS); // 2^-26 exact
        float loss = s * inv * 0.1f;
        out[0] = loss;
        out[1] = 0.5f * loss;
    }
}

extern "C" void kernel_launch(void* const* d_in, const int* in_sizes, int n_in,
                              void* d_out, int out_size, void* d_ws, size_t ws_size,
                              hipStream_t stream)
{
    const float* X = (const float*)d_in[0];
    float* out = (float*)d_out;

    char* ws = (char*)d_ws;
    float*         acc   = (float*)ws;                   // NACC fp32 slots
    float*         norms = (float*)(ws + 1024);          // 8192 fp32 (32 KB)
    unsigned char* Xq    = (unsigned char*)(ws + 1024 + 32768); // fp8 X, 4 MB

    norm_convert_kernel<<<NROWS / 4, 256, 0, stream>>>(X, Xq, norms, acc);
    pair_loss_gemm_kernel<<<NTRI, 256, 0, stream>>>(Xq, norms, acc);
    finalize_kernel<<<1, 64, 0, stream>>>(acc, out);
}